// Round 9
// baseline (452.533 us; speedup 1.0000x reference)
//
#include <hip/hip_runtime.h>
#include <math.h>

// ===========================================================================
// PCSQCNN fully fused: FRQI encode -> [QFT2D -> mux -> IQFT2D -> pool]^3
//                      -> |.|^2 -> linear
//
// Round 10: fused kfuse (one block/image, 32 float2 state/thread).
// Rounds 11-16: six attempts to lift the 64-VGPR allocation -> ALL null.
//   VGPR=64 is hard toolchain behavior for this kernel; state spills to
//   scratch (~300 MB round-trip), partially hidden by 2 WG/CU.
// Round 17: 2WG/CU + zero-aggregate combined -> 295 us (effects did not
//   compose; same as rounds 15/16).
// Round 18 (this round): LDS B64 CONVERSION. Instruction-count model:
//   SoA x/y float planes cost 2x ds_b32 per float2 moved; ~4500 ds_b32 per
//   thread => >=120us of pure LDS instruction stream per kernel. Fix:
//   merge Xp/Yp into ONE interleaved float2 buffer; every LDS access
//   becomes a single ds_*_b64 (half the instructions, half the LDS address
//   VALU, same bytes). XOR masks (13/22) spread the hot ownership patterns
//   (S=1/8/32) to the 4-access/bank-pair b64 floor. All indices, barriers,
//   ownerships byte-identical to round 17. LDS total unchanged (66048 B,
//   2 WG/CU).
//   PIVOT: if <5% gain, kernel is scratch-latency-bound -> next round is
//   the LDS-parked split-plane design (no scratch, <=64 VGPR by design).
//
// U tables (k0): U0 transposed [y_st][x_st]; U1 unchanged;
// U2 stored [yam][cx][cy][xam] so mux loads are 128B-contiguous/thread.
// Ownerships: F = {2j,2j+1,64+2j,65+2j}; F4 = {fb,fb+16,fb+64,fb+80},
// fb=(j>>4)*32+(j&15).
// ===========================================================================

#define PI_F 3.14159265358979323846f
#define P_ 128

__device__ __forceinline__ float2 cmul(float2 a, float2 b) {
    return make_float2(a.x * b.x - a.y * b.y, a.x * b.y + a.y * b.x);
}
__device__ __forceinline__ float2 cadd(float2 a, float2 b) {
    return make_float2(a.x + b.x, a.y + b.y);
}
__device__ __forceinline__ float2 scl(float2 a, float s) {
    return make_float2(a.x * s, a.y * s);
}
__device__ __forceinline__ void bfly_dif(float2& u, float2& v, float2 w) {
    float tx = u.x - v.x, ty = u.y - v.y;
    u.x += v.x; u.y += v.y;
    v.x = tx * w.x - ty * w.y;
    v.y = tx * w.y + ty * w.x;
}
__device__ __forceinline__ void bfly_dif1(float2& u, float2& v) {
    float tx = u.x - v.x, ty = u.y - v.y;
    u.x += v.x; u.y += v.y;
    v.x = tx; v.y = ty;
}
__device__ __forceinline__ void bfly_dit(float2& u, float2& v, float2 w) {
    float tx = v.x * w.x + v.y * w.y, ty = v.y * w.x - v.x * w.y;
    v.x = u.x - tx; v.y = u.y - ty;
    u.x += tx; u.y += ty;
}
__device__ __forceinline__ void bfly_dit1(float2& u, float2& v) {
    float tx = v.x, ty = v.y;
    v.x = u.x - tx; v.y = u.y - ty;
    u.x += tx; u.y += ty;
}

constexpr int clog2(int v) { return v <= 1 ? 0 : 1 + clog2(v >> 1); }

// LDS exchange address: line L, idx 0..127, XOR bank swizzle (bijective).
// Index is in float2 units (b64 ops).
__device__ __forceinline__ int pf(int L, int idx) {
    int m = ((idx & 32) ? 13 : 0) ^ ((idx & 64) ? 22 : 0);
    return L * P_ + (idx ^ m);
}

// Ownership (scalar outputs): thread j owns base + {0,1,2,3}*S within
// segment of size N; o = jj % S.
template <int N, int S>
__device__ __forceinline__ void oidxs(int j, int& i0, int& i1, int& i2,
                                      int& i3, int& o) {
    constexpr int TPS = N / 4;
    constexpr int LT = clog2(TPS);
    int s = j >> LT;
    int jj = j & (TPS - 1);
    o = jj & (S - 1);
    int base = s * N + ((jj & ~(S - 1)) << 2) + o;
    i0 = base; i1 = base + S; i2 = base + 2 * S; i3 = base + 3 * S;
}

// Two DIF levels h=2S then h=S (reference args; no aggregates)
template <int S>
__device__ __forceinline__ void difp(float2& A, float2& B, float2& C,
                                     float2& D, int o, const float2* tw) {
    bfly_dif(A, C, tw[o * (32 / S)]);
    bfly_dif(B, D, tw[(o + S) * (32 / S)]);
    float2 wc = tw[o * (64 / S)];
    bfly_dif(A, B, wc);
    bfly_dif(C, D, wc);
}
template <int S>
__device__ __forceinline__ void ditp(float2& A, float2& B, float2& C,
                                     float2& D, int o, const float2* tw) {
    float2 wc = tw[o * (64 / S)];
    bfly_dit(A, B, wc);
    bfly_dit(C, D, wc);
    bfly_dit(A, C, tw[o * (32 / S)]);
    bfly_dit(B, D, tw[(o + S) * (32 / S)]);
}

// One exchange round for a line pair; crew-local (32 lanes of one wave),
// wave_barrier suffices. Single float2 buffer -> ds_*_b64 per float2.
__device__ __forceinline__ void xch2s(float2* Bf, int la, int lb,
                                      int w0, int w1, int w2, int w3,
                                      int e0, int e1, int e2, int e3,
                                      float2& A0, float2& A1, float2& A2,
                                      float2& A3, float2& B0, float2& B1,
                                      float2& B2, float2& B3) {
    Bf[pf(la, w0)] = A0; Bf[pf(lb, w0)] = B0;
    Bf[pf(la, w1)] = A1; Bf[pf(lb, w1)] = B1;
    Bf[pf(la, w2)] = A2; Bf[pf(lb, w2)] = B2;
    Bf[pf(la, w3)] = A3; Bf[pf(lb, w3)] = B3;
    __builtin_amdgcn_wave_barrier();
    A0 = Bf[pf(la, e0)]; B0 = Bf[pf(lb, e0)];
    A1 = Bf[pf(la, e1)]; B1 = Bf[pf(lb, e1)];
    A2 = Bf[pf(la, e2)]; B2 = Bf[pf(lb, e2)];
    A3 = Bf[pf(la, e3)]; B3 = Bf[pf(lb, e3)];
    __builtin_amdgcn_wave_barrier();
}

// 2x2 multiplex on feature pair with table entry U[0..3]
__device__ __forceinline__ void muxop(const float2* __restrict__ U,
                                      float2& a, float2& b) {
    float2 p0 = a, p1 = b;
    a = cadd(cmul(U[0], p0), cmul(U[1], p1));
    b = cadd(cmul(U[2], p0), cmul(U[3], p1));
}

// ---- whole-state macros over the 32 named scalars v00..v73 ----------------
#define DIF8(S, O) { \
    difp<S>(v00, v01, v02, v03, O, tw); difp<S>(v10, v11, v12, v13, O, tw); \
    difp<S>(v20, v21, v22, v23, O, tw); difp<S>(v30, v31, v32, v33, O, tw); \
    difp<S>(v40, v41, v42, v43, O, tw); difp<S>(v50, v51, v52, v53, O, tw); \
    difp<S>(v60, v61, v62, v63, O, tw); difp<S>(v70, v71, v72, v73, O, tw); }
#define DIT8(S, O) { \
    ditp<S>(v00, v01, v02, v03, O, tw); ditp<S>(v10, v11, v12, v13, O, tw); \
    ditp<S>(v20, v21, v22, v23, O, tw); ditp<S>(v30, v31, v32, v33, O, tw); \
    ditp<S>(v40, v41, v42, v43, O, tw); ditp<S>(v50, v51, v52, v53, O, tw); \
    ditp<S>(v60, v61, v62, v63, O, tw); ditp<S>(v70, v71, v72, v73, O, tw); }

// exchange of all 8 lines; rounds (0,4),(1,5),(2,6),(3,7) as before
#define XCHC(W0, W1, W2, W3, E0, E1, E2, E3) { \
    xch2s(Bf, la, lb, W0, W1, W2, W3, E0, E1, E2, E3, \
          v00, v01, v02, v03, v40, v41, v42, v43); \
    xch2s(Bf, la, lb, W0, W1, W2, W3, E0, E1, E2, E3, \
          v10, v11, v12, v13, v50, v51, v52, v53); \
    xch2s(Bf, la, lb, W0, W1, W2, W3, E0, E1, E2, E3, \
          v20, v21, v22, v23, v60, v61, v62, v63); \
    xch2s(Bf, la, lb, W0, W1, W2, W3, E0, E1, E2, E3, \
          v30, v31, v32, v33, v70, v71, v72, v73); }

#define XCALL(NW, SW, NR, SR) { \
    int w0_, w1_, w2_, w3_, e0_, e1_, e2_, e3_, ou_; \
    oidxs<NW, SW>(j, w0_, w1_, w2_, w3_, ou_); (void)ou_; \
    oidxs<NR, SR>(j, e0_, e1_, e2_, e3_, o); \
    XCHC(w0_, w1_, w2_, w3_, e0_, e1_, e2_, e3_) }

#define H1F8() { \
    bfly_dif1(v00, v01); bfly_dif1(v02, v03); bfly_dif1(v10, v11); bfly_dif1(v12, v13); \
    bfly_dif1(v20, v21); bfly_dif1(v22, v23); bfly_dif1(v30, v31); bfly_dif1(v32, v33); \
    bfly_dif1(v40, v41); bfly_dif1(v42, v43); bfly_dif1(v50, v51); bfly_dif1(v52, v53); \
    bfly_dif1(v60, v61); bfly_dif1(v62, v63); bfly_dif1(v70, v71); bfly_dif1(v72, v73); }
#define H1T8() { \
    bfly_dit1(v00, v01); bfly_dit1(v02, v03); bfly_dit1(v10, v11); bfly_dit1(v12, v13); \
    bfly_dit1(v20, v21); bfly_dit1(v22, v23); bfly_dit1(v30, v31); bfly_dit1(v32, v33); \
    bfly_dit1(v40, v41); bfly_dit1(v42, v43); bfly_dit1(v50, v51); bfly_dit1(v52, v53); \
    bfly_dit1(v60, v61); bfly_dit1(v62, v63); bfly_dit1(v70, v71); bfly_dit1(v72, v73); }
#define H64_8(WA, WB) { \
    bfly_dit(v00, v02, WA); bfly_dit(v01, v03, WB); bfly_dit(v10, v12, WA); bfly_dit(v11, v13, WB); \
    bfly_dit(v20, v22, WA); bfly_dit(v21, v23, WB); bfly_dit(v30, v32, WA); bfly_dit(v31, v33, WB); \
    bfly_dit(v40, v42, WA); bfly_dit(v41, v43, WB); bfly_dit(v50, v52, WA); bfly_dit(v51, v53, WB); \
    bfly_dit(v60, v62, WA); bfly_dit(v61, v63, WB); bfly_dit(v70, v72, WA); bfly_dit(v71, v73, WB); }
#define FH8(WC) { \
    bfly_dif(v00, v01, WC); bfly_dif(v02, v03, WC); bfly_dif(v10, v11, WC); bfly_dif(v12, v13, WC); \
    bfly_dif(v20, v21, WC); bfly_dif(v22, v23, WC); bfly_dif(v30, v31, WC); bfly_dif(v32, v33, WC); \
    bfly_dif(v40, v41, WC); bfly_dif(v42, v43, WC); bfly_dif(v50, v51, WC); bfly_dif(v52, v53, WC); \
    bfly_dif(v60, v61, WC); bfly_dif(v62, v63, WC); bfly_dif(v70, v71, WC); bfly_dif(v72, v73, WC); }
#define H16P8(WC) { \
    bfly_dit(v00, v01, WC); bfly_dit(v02, v03, WC); bfly_dit(v10, v11, WC); bfly_dit(v12, v13, WC); \
    bfly_dit(v20, v21, WC); bfly_dit(v22, v23, WC); bfly_dit(v30, v31, WC); bfly_dit(v32, v33, WC); \
    bfly_dit(v40, v41, WC); bfly_dit(v42, v43, WC); bfly_dit(v50, v51, WC); bfly_dit(v52, v53, WC); \
    bfly_dit(v60, v61, WC); bfly_dit(v62, v63, WC); bfly_dit(v70, v71, WC); bfly_dit(v72, v73, WC); }
#define SC8(SCV) { const float sc_ = (SCV); \
    v00 = scl(v00, sc_); v01 = scl(v01, sc_); v02 = scl(v02, sc_); v03 = scl(v03, sc_); \
    v10 = scl(v10, sc_); v11 = scl(v11, sc_); v12 = scl(v12, sc_); v13 = scl(v13, sc_); \
    v20 = scl(v20, sc_); v21 = scl(v21, sc_); v22 = scl(v22, sc_); v23 = scl(v23, sc_); \
    v30 = scl(v30, sc_); v31 = scl(v31, sc_); v32 = scl(v32, sc_); v33 = scl(v33, sc_); \
    v40 = scl(v40, sc_); v41 = scl(v41, sc_); v42 = scl(v42, sc_); v43 = scl(v43, sc_); \
    v50 = scl(v50, sc_); v51 = scl(v51, sc_); v52 = scl(v52, sc_); v53 = scl(v53, sc_); \
    v60 = scl(v60, sc_); v61 = scl(v61, sc_); v62 = scl(v62, sc_); v63 = scl(v63, sc_); \
    v70 = scl(v70, sc_); v71 = scl(v71, sc_); v72 = scl(v72, sc_); v73 = scl(v73, sc_); }

#define SWP(A, B) { float2 t_ = A; A = B; B = t_; }
// register 4x4 transpose per f-block (pure renaming after regalloc)
#define XPOSE44() { \
    SWP(v01, v10) SWP(v02, v20) SWP(v03, v30) SWP(v12, v21) SWP(v13, v31) SWP(v23, v32) \
    SWP(v41, v50) SWP(v42, v60) SWP(v43, v70) SWP(v52, v61) SWP(v53, v71) SWP(v63, v72) }

// Transpose A: store line at Y-positions is0..is3 (rotation swizzle), reload
// at new X line XL with Y positions g+32d. Single-buffer b64 accesses.
#define TPA_ST(R0, R1, R2, R3, XL) { const int Xl_ = (XL); \
    Bf[Xl_ * P_ + ((is0 + Xl_) & 127)] = R0; \
    Bf[Xl_ * P_ + ((is1 + Xl_) & 127)] = R1; \
    Bf[Xl_ * P_ + ((is2 + Xl_) & 127)] = R2; \
    Bf[Xl_ * P_ + ((is3 + Xl_) & 127)] = R3; }
#define TPA_LD(R0, R1, R2, R3, XL) { const int Xl_ = (XL); \
    R0 = Bf[Xl_ * P_ + ((g + Xl_) & 127)]; \
    R1 = Bf[Xl_ * P_ + ((g + 32 + Xl_) & 127)]; \
    R2 = Bf[Xl_ * P_ + ((g + 64 + Xl_) & 127)]; \
    R3 = Bf[Xl_ * P_ + ((g + 96 + Xl_) & 127)]; }
#define TPA_CHUNK(RA0, RA1, RA2, RA3, RB0, RB1, RB2, RB3, XLA, XLB) { \
    __syncthreads(); \
    TPA_ST(RA0, RA1, RA2, RA3, g) TPA_ST(RB0, RB1, RB2, RB3, g + 32) \
    __syncthreads(); \
    TPA_LD(RA0, RA1, RA2, RA3, XLA) TPA_LD(RB0, RB1, RB2, RB3, XLB) }

// Transpose B: store line at X-line from is (positions g+32d), reload at
// Y-positions id0..id3.
#define TPB_ST(R0, R1, R2, R3, ISL) { const int Xl_ = (ISL) & 63; \
    Bf[Xl_ * P_ + ((g + Xl_) & 127)]      = R0; \
    Bf[Xl_ * P_ + ((g + 32 + Xl_) & 127)] = R1; \
    Bf[Xl_ * P_ + ((g + 64 + Xl_) & 127)] = R2; \
    Bf[Xl_ * P_ + ((g + 96 + Xl_) & 127)] = R3; }
#define TPB_LD(R0, R1, R2, R3, XL) { const int Xl_ = (XL); \
    R0 = Bf[Xl_ * P_ + ((id0 + Xl_) & 127)]; \
    R1 = Bf[Xl_ * P_ + ((id1 + Xl_) & 127)]; \
    R2 = Bf[Xl_ * P_ + ((id2 + Xl_) & 127)]; \
    R3 = Bf[Xl_ * P_ + ((id3 + Xl_) & 127)]; }
#define TPB_CHUNK(RA0, RA1, RA2, RA3, RB0, RB1, RB2, RB3, ISA, ISB) { \
    __syncthreads(); \
    TPB_ST(RA0, RA1, RA2, RA3, ISA) TPB_ST(RB0, RB1, RB2, RB3, ISB) \
    __syncthreads(); \
    TPB_LD(RA0, RA1, RA2, RA3, g) TPB_LD(RB0, RB1, RB2, RB3, g + 32) }

// ---------------------------------------------------------------------------
// K0: precompute multiplex U tables, pre-permuted by bit-reversal (unchanged).
// ---------------------------------------------------------------------------
__global__ __launch_bounds__(256) void k0_prep(const float* __restrict__ mux0,
                                               const float* __restrict__ mux1,
                                               const float* __restrict__ mux2,
                                               float2* __restrict__ U0,
                                               float2* __restrict__ U1,
                                               float2* __restrict__ U2) {
    int t = blockIdx.x * 256 + threadIdx.x;
    const float* src;
    float2* dst;
    if (t < 16384) {
        int xb = t >> 7, yb = t & 127;
        int rx = __brev((unsigned)xb) >> 25;
        int ry = __brev((unsigned)yb) >> 25;
        src = mux0 + ((size_t)rx * 128 + ry) * 3;
        dst = U0 + ((size_t)yb * 128 + xb) * 4;
    } else if (t < 32768) {
        int u = t - 16384;
        int yam = u & 63, xam = (u >> 6) & 63, cy = (u >> 12) & 1, cx = (u >> 13) & 1;
        int rx = __brev((unsigned)xam) >> 26;
        int ry = __brev((unsigned)yam) >> 26;
        src = mux1 + ((size_t)(((cx * 2 + cy) * 64 + rx) * 64 + ry)) * 3;
        dst = U1 + (size_t)u * 4;
    } else if (t < 36864) {
        int u = t - 32768;
        int yam = u & 31, xam = (u >> 5) & 31, cy = (u >> 10) & 1, cx = (u >> 11) & 1;
        int rx = __brev((unsigned)xam) >> 27;
        int ry = __brev((unsigned)yam) >> 27;
        src = mux2 + ((size_t)(((cx * 2 + cy) * 32 + rx) * 32 + ry)) * 3;
        dst = U2 + ((size_t)(((yam * 2 + cx) * 2 + cy) * 32 + xam)) * 4;
    } else {
        return;
    }
    float ax = src[0], ay = src[1], az = src[2];
    float r = sqrtf(ax * ax + ay * ay + az * az + 1e-20f);
    float cr = cosf(r);
    float snr = sinf(r) / r;
    dst[0] = make_float2(cr, -az * snr);
    dst[1] = make_float2(-ay * snr, -ax * snr);
    dst[2] = make_float2(ay * snr, -ax * snr);
    dst[3] = make_float2(cr, az * snr);
}

// ---------------------------------------------------------------------------
// KFUSE: whole pipeline per image. 1024 threads = 32 crews x 32 lanes.
// State = 32 named float2 scalars. LDS: ONE interleaved float2 buffer
// (8192 fl2 = 64KB) + tw -> ds_*_b64 ops, 66048 B dynamic -> 2 WG/CU.
// ---------------------------------------------------------------------------
__global__ __attribute__((amdgpu_flat_work_group_size(1024, 1024)))
void kfuse(const float* __restrict__ img,
           const float2* __restrict__ U0,
           const float2* __restrict__ U1,
           const float2* __restrict__ U2,
           float* __restrict__ prob) {
    extern __shared__ float2 smem2[];
    float2* Bf = smem2;                     // 8192 float2 (exchange buffer)
    float2* tw = smem2 + 8192;              // 64 float2

    const int tid = threadIdx.x;
    const int b = blockIdx.x;
    const int g = tid >> 5;
    const int j = tid & 31;
    const int la = 2 * g, lb = 2 * g + 1;

    if (tid < 64) {
        float ang = -(2.0f * PI_F / 128.0f) * (float)tid;  // |ang| < 2pi
        tw[tid] = make_float2(__cosf(ang), __sinf(ang));
    }

    // state: 32 named float2 scalars, vKq = line K, element q
    float2 v00, v01, v02, v03, v10, v11, v12, v13;
    float2 v20, v21, v22, v23, v30, v31, v32, v33;
    float2 v40, v41, v42, v43, v50, v51, v52, v53;
    float2 v60, v61, v62, v63, v70, v71, v72, v73;
    int o;

    // ================= pass 1 (Y): FRQI encode + FFT_Y128 =================
    {
        const float* ib = img + (size_t)b * 16384;
        const float S128 = 1.0f / 128.0f;
#define ENC_K(K, A0, A1, A2, A3, B0, B1, B2, B3) { \
        const float* ip = ib + (g + 32 * (K)) * 128; \
        { float ang = 0.5f * PI_F * ip[j];      A0 = make_float2(__cosf(ang) * S128, 0.0f); B0 = make_float2(__sinf(ang) * S128, 0.0f); } \
        { float ang = 0.5f * PI_F * ip[j + 32]; A1 = make_float2(__cosf(ang) * S128, 0.0f); B1 = make_float2(__sinf(ang) * S128, 0.0f); } \
        { float ang = 0.5f * PI_F * ip[j + 64]; A2 = make_float2(__cosf(ang) * S128, 0.0f); B2 = make_float2(__sinf(ang) * S128, 0.0f); } \
        { float ang = 0.5f * PI_F * ip[j + 96]; A3 = make_float2(__cosf(ang) * S128, 0.0f); B3 = make_float2(__sinf(ang) * S128, 0.0f); } }
        ENC_K(0, v00, v01, v02, v03, v40, v41, v42, v43)
        ENC_K(1, v10, v11, v12, v13, v50, v51, v52, v53)
        ENC_K(2, v20, v21, v22, v23, v60, v61, v62, v63)
        ENC_K(3, v30, v31, v32, v33, v70, v71, v72, v73)
#undef ENC_K
    }
    __syncthreads();  // tw visible
    DIF8(32, j)                                   // h=64,32
    XCALL(128, 32, 128, 8)
    DIF8(8, o)                                    // h=16,8
    XCALL(128, 8, 128, 2)
    DIF8(2, o)                                    // h=4,2
    XCALL(128, 2, 128, 1)
    H1F8()                                        // h=1

    // ================= T_A1 (MODE 0) =================
    {
        const int is0 = 4 * j, is1 = 4 * j + 1, is2 = 4 * j + 2, is3 = 4 * j + 3;
        TPA_CHUNK(v00, v01, v02, v03, v10, v11, v12, v13, j, j + 32)
        TPA_CHUNK(v20, v21, v22, v23, v30, v31, v32, v33, j, j + 32)
        TPA_CHUNK(v40, v41, v42, v43, v50, v51, v52, v53, j, j + 32)
        TPA_CHUNK(v60, v61, v62, v63, v70, v71, v72, v73, j, j + 32)
        __syncthreads();
        XPOSE44()
    }

    // ====== pass 2 (X): FFT_X128 -> M0 -> IFFT_X128 -> FFT_X64 ======
    DIF8(32, j)
    XCALL(128, 32, 128, 8)
    DIF8(8, o)
    XCALL(128, 8, 128, 2)
    DIF8(2, o)
    XCALL(128, 2, 128, 1)
    H1F8()
    // M0 at x_st = 4j+q, y_st = g+32k (register-local f pair)
    {
#define MUX0_K(K, A0, A1, A2, A3, B0, B1, B2, B3) { \
        const float2* Ub = U0 + ((size_t)(g + 32 * (K)) * 128 + 4 * j) * 4; \
        muxop(Ub + 0, A0, B0); muxop(Ub + 4, A1, B1); \
        muxop(Ub + 8, A2, B2); muxop(Ub + 12, A3, B3); }
        MUX0_K(0, v00, v01, v02, v03, v40, v41, v42, v43)
        MUX0_K(1, v10, v11, v12, v13, v50, v51, v52, v53)
        MUX0_K(2, v20, v21, v22, v23, v60, v61, v62, v63)
        MUX0_K(3, v30, v31, v32, v33, v70, v71, v72, v73)
#undef MUX0_K
    }
    // IFFT_X128: [1,2] -> [4,8] -> [16,32] -> [64]
    DIT8(1, 0)
    XCALL(128, 1, 128, 4)
    DIT8(4, o)
    XCALL(128, 4, 128, 16)
    DIT8(16, o)
    XCALL(128, 16, 128, 32)
    { const float2 wA = tw[o], wB = tw[o + 32]; H64_8(wA, wB) }   // h=64
    { const float2 wC = tw[2 * o]; FH8(wC) }                      // FFT64 h=32
    XCALL(128, 32, 64, 8)
    DIF8(8, o)                                    // FFT64 h=16,8
    XCALL(64, 8, 64, 2)
    DIF8(2, o)                                    // h=4,2
    {   // -> F ownership (needed by T_B1)
        int w0_, w1_, w2_, w3_, ou_;
        oidxs<64, 2>(j, w0_, w1_, w2_, w3_, ou_); (void)ou_;
        const int e0_ = 2 * j, e1_ = 2 * j + 1, e2_ = 64 + 2 * j, e3_ = 65 + 2 * j;
        XCHC(w0_, w1_, w2_, w3_, e0_, e1_, e2_, e3_)
    }
    H1F8()                                        // h=1
    SC8(1.0f / 128.0f)                            // IFFT128 norm

    // ================= T_B1 =================
    {
        const int is0 = 2 * j, is1 = 2 * j + 1, is2 = 64 + 2 * j, is3 = 65 + 2 * j;
        const int id0 = 4 * j, id1 = 4 * j + 1, id2 = 4 * j + 2, id3 = 4 * j + 3;
        XPOSE44()
        TPB_CHUNK(v00, v01, v02, v03, v10, v11, v12, v13, is0, is1)
        TPB_CHUNK(v20, v21, v22, v23, v30, v31, v32, v33, is2, is3)
        TPB_CHUNK(v40, v41, v42, v43, v50, v51, v52, v53, is0, is1)
        TPB_CHUNK(v60, v61, v62, v63, v70, v71, v72, v73, is2, is3)
        __syncthreads();
    }

    // == pass 3 (Y): IFFT_Y128 -> FFT_Y64 -> M1 -> IFFT_Y64 -> FFT_Y32 ==
    DIT8(1, 0)
    XCALL(128, 1, 128, 4)
    DIT8(4, o)
    XCALL(128, 4, 128, 16)
    DIT8(16, o)
    XCALL(128, 16, 128, 32)
    { const float2 wA = tw[o], wB = tw[o + 32]; H64_8(wA, wB) }
    { const float2 wC = tw[2 * o]; FH8(wC) }
    XCALL(128, 32, 64, 8)
    DIF8(8, o)
    XCALL(64, 8, 64, 2)
    DIF8(2, o)
    XCALL(64, 2, 64, 1)
    H1F8()
    // M1: y_st = s*64 + 4jj + q; lines x_st = g+32k
    {
        const int s = j >> 4, jj = j & 15;
#define MUX1_K(CX, KB, A0, A1, A2, A3, B0, B1, B2, B3) { \
        const int xam = g + 32 * (KB); \
        const float2* Ub = U1 + \
            ((size_t)(((((((CX) << 1) | s) << 6) | xam) << 6) | (4 * jj))) * 4; \
        muxop(Ub + 0, A0, B0); muxop(Ub + 4, A1, B1); \
        muxop(Ub + 8, A2, B2); muxop(Ub + 12, A3, B3); }
        MUX1_K(0, 0, v00, v01, v02, v03, v40, v41, v42, v43)
        MUX1_K(0, 1, v10, v11, v12, v13, v50, v51, v52, v53)
        MUX1_K(1, 0, v20, v21, v22, v23, v60, v61, v62, v63)
        MUX1_K(1, 1, v30, v31, v32, v33, v70, v71, v72, v73)
#undef MUX1_K
    }
    // IFFT_Y64: [1,2] -> [4,8] -> [16,32]
    DIT8(1, 0)
    XCALL(64, 1, 64, 4)
    DIT8(4, o)
    XCALL(64, 4, 64, 16)
    DIT8(16, o)
    { const float2 wC = tw[4 * o]; FH8(wC) }      // fused FFT32 h=16
    XCALL(64, 16, 32, 4)
    DIF8(4, o)                                    // FFT32 h=8,4
    XCALL(32, 4, 32, 1)
    DIF8(1, 0)                                    // h=2,1
    SC8(1.0f / 8192.0f)                           // IFFT128*IFFT64

    // ================= T_A2 (MODE 1, dest positions = F) =================
    {
        int is0, is1, is2, is3, ou_;
        oidxs<32, 1>(j, is0, is1, is2, is3, ou_); (void)ou_;
        TPA_CHUNK(v00, v01, v02, v03, v10, v11, v12, v13, 2 * j, 2 * j + 1)
        TPA_CHUNK(v20, v21, v22, v23, v30, v31, v32, v33, 2 * j, 2 * j + 1)
        TPA_CHUNK(v40, v41, v42, v43, v50, v51, v52, v53, 2 * j, 2 * j + 1)
        TPA_CHUNK(v60, v61, v62, v63, v70, v71, v72, v73, 2 * j, 2 * j + 1)
        __syncthreads();
        XPOSE44()
    }

    // ====== pass 4 (X): IFFT_X64 -> FFT_X32 -> M2 -> IFFT_X32 ======
    H1T8()                                        // h=1 at F (w=1)
    {
        const int w0_ = 2 * j, w1_ = 2 * j + 1, w2_ = 64 + 2 * j, w3_ = 65 + 2 * j;
        int e0_, e1_, e2_, e3_;
        oidxs<64, 2>(j, e0_, e1_, e2_, e3_, o);
        XCHC(w0_, w1_, w2_, w3_, e0_, e1_, e2_, e3_)
    }
    DIT8(2, o)                                    // h=2,4
    XCALL(64, 2, 64, 8)
    DIT8(8, o)                                    // h=8,16
    XCALL(64, 8, 64, 16)
    { const float2 wA = tw[2 * o], wB = tw[2 * (o + 16)]; H64_8(wA, wB) }  // h=32
    { const float2 wC = tw[4 * o]; FH8(wC) }      // fused FFT32 h=16
    XCALL(64, 16, 32, 4)
    DIF8(4, o)
    XCALL(32, 4, 32, 1)
    DIF8(1, 0)
    // M2: x_st = s4*32 + 4jj8 + q; lines y_st = g+32k
    {
        const int s4 = j >> 3, jj8 = j & 7;
#define MUX2_K(KB, A0, A1, A2, A3, B0, B1, B2, B3) { \
        const float2* Ub = U2 + \
            ((size_t)((((g << 2) | ((s4 & 1) << 1) | (KB)) << 5) | (4 * jj8))) * 4; \
        muxop(Ub + 0, A0, B0); muxop(Ub + 4, A1, B1); \
        muxop(Ub + 8, A2, B2); muxop(Ub + 12, A3, B3); }
        MUX2_K(0, v00, v01, v02, v03, v40, v41, v42, v43)
        MUX2_K(1, v10, v11, v12, v13, v50, v51, v52, v53)
        MUX2_K(0, v20, v21, v22, v23, v60, v61, v62, v63)
        MUX2_K(1, v30, v31, v32, v33, v70, v71, v72, v73)
#undef MUX2_K
    }
    // IFFT_X32: [1,2] -> [4,8] -> [16] (end at F4 for T_B2)
    DIT8(1, 0)
    XCALL(32, 1, 32, 4)
    DIT8(4, o)
    {
        int w0_, w1_, w2_, w3_, ou_;
        oidxs<32, 4>(j, w0_, w1_, w2_, w3_, ou_); (void)ou_;
        const int fb_ = (j >> 4) * 32 + (j & 15);
        const int e0_ = fb_, e1_ = fb_ + 16, e2_ = fb_ + 64, e3_ = fb_ + 80;
        XCHC(w0_, w1_, w2_, w3_, e0_, e1_, e2_, e3_)
    }
    {
        const int m = j & 15;
        const float2 wC = tw[4 * m];
        H16P8(wC)                                 // h=16
        SC8(1.0f / 2048.0f)                       // IFFT64*IFFT32
    }

    // ================= T_B2 =================
    {
        const int fb_ = (j >> 4) * 32 + (j & 15);
        const int is0 = fb_, is1 = fb_ + 16, is2 = fb_ + 64, is3 = fb_ + 80;
        int id0, id1, id2, id3, ou_;
        oidxs<32, 1>(j, id0, id1, id2, id3, ou_); (void)ou_;
        XPOSE44()
        TPB_CHUNK(v00, v01, v02, v03, v10, v11, v12, v13, is0, is1)
        TPB_CHUNK(v20, v21, v22, v23, v30, v31, v32, v33, is2, is3)
        TPB_CHUNK(v40, v41, v42, v43, v50, v51, v52, v53, is0, is1)
        TPB_CHUNK(v60, v61, v62, v63, v70, v71, v72, v73, is2, is3)
        __syncthreads();
    }

    // ========== pass 5 (Y): IFFT_Y32 + |.|^2 marginal ==========
    DIT8(1, 0)
    XCALL(32, 1, 32, 4)
    DIT8(4, o)
    XCALL(32, 4, 32, 8)
    { const float2 wA = tw[4 * o], wB = tw[4 * o + 32]; H64_8(wA, wB) }  // h=16
    // prob: sum over xc (in-thread lines) and yc (= j>>3, via shfl)
    {
#define SQ2(v) ((v).x * (v).x + (v).y * (v).y)
        float s00 = SQ2(v00) + SQ2(v10) + SQ2(v20) + SQ2(v30);
        float s01 = SQ2(v01) + SQ2(v11) + SQ2(v21) + SQ2(v31);
        float s02 = SQ2(v02) + SQ2(v12) + SQ2(v22) + SQ2(v32);
        float s03 = SQ2(v03) + SQ2(v13) + SQ2(v23) + SQ2(v33);
        float s10 = SQ2(v40) + SQ2(v50) + SQ2(v60) + SQ2(v70);
        float s11 = SQ2(v41) + SQ2(v51) + SQ2(v61) + SQ2(v71);
        float s12 = SQ2(v42) + SQ2(v52) + SQ2(v62) + SQ2(v72);
        float s13 = SQ2(v43) + SQ2(v53) + SQ2(v63) + SQ2(v73);
#undef SQ2
        s00 += __shfl_xor(s00, 8); s00 += __shfl_xor(s00, 16);
        s01 += __shfl_xor(s01, 8); s01 += __shfl_xor(s01, 16);
        s02 += __shfl_xor(s02, 8); s02 += __shfl_xor(s02, 16);
        s03 += __shfl_xor(s03, 8); s03 += __shfl_xor(s03, 16);
        s10 += __shfl_xor(s10, 8); s10 += __shfl_xor(s10, 16);
        s11 += __shfl_xor(s11, 8); s11 += __shfl_xor(s11, 16);
        s12 += __shfl_xor(s12, 8); s12 += __shfl_xor(s12, 16);
        s13 += __shfl_xor(s13, 8); s13 += __shfl_xor(s13, 16);
        if ((j >> 3) == 0) {
            const int jj = j & 7;
            const float C = 1.0f / 1024.0f;
            float2* pp = (float2*)(prob + (size_t)(b * 32 + g) * 64);
            pp[jj +  0] = make_float2(s00 * C, s10 * C);
            pp[jj +  8] = make_float2(s01 * C, s11 * C);
            pp[jj + 16] = make_float2(s02 * C, s12 * C);
            pp[jj + 24] = make_float2(s03 * C, s13 * C);
        }
    }
}

// ---------------------------------------------------------------------------
// K6: linear head, wave-shuffle reduction (unchanged).
// ---------------------------------------------------------------------------
__global__ __launch_bounds__(256) void k6_linear(const float* __restrict__ prob,
                                                 const float* __restrict__ W,
                                                 const float* __restrict__ bv,
                                                 float* __restrict__ out) {
    __shared__ float red[40];
    int b = blockIdx.x;
    int tid = threadIdx.x;
    float acc[10];
#pragma unroll
    for (int c = 0; c < 10; ++c) acc[c] = 0.0f;
    for (int j = tid; j < 2048; j += 256) {
        float p = prob[(size_t)b * 2048 + j];
#pragma unroll
        for (int c = 0; c < 10; ++c) acc[c] += p * W[c * 2048 + j];
    }
    int wv = tid >> 6, ln = tid & 63;
#pragma unroll
    for (int c = 0; c < 10; ++c) {
        float s = acc[c];
        for (int off = 32; off > 0; off >>= 1) s += __shfl_down(s, off);
        if (ln == 0) red[wv * 10 + c] = s;
    }
    __syncthreads();
    if (tid < 10)
        out[b * 10 + tid] =
            red[tid] + red[10 + tid] + red[20 + tid] + red[30 + tid] + bv[tid];
}

// ---------------------------------------------------------------------------
extern "C" void kernel_launch(void* const* d_in, const int* in_sizes, int n_in,
                              void* d_out, int out_size, void* d_ws,
                              size_t ws_size, hipStream_t stream) {
    const float* images = (const float*)d_in[0];
    const float* mux0 = (const float*)d_in[1];
    const float* mux1 = (const float*)d_in[2];
    const float* mux2 = (const float*)d_in[3];
    const float* W = (const float*)d_in[4];
    const float* bv = (const float*)d_in[5];
    float* out = (float*)d_out;

    float2* U0 = (float2*)d_ws;
    float2* U1 = U0 + 65536;
    float2* U2 = U1 + 65536;
    float* prob = (float*)(U2 + 16384);
    const size_t needed =
        (size_t)(65536 + 65536 + 16384) * sizeof(float2) +
        (size_t)512 * 2048 * sizeof(float);
    if (ws_size < needed) return;

    const int LDS_BYTES = (8192 + 64) * 8;    // fl2 buffer + tw = 66048 B
                                              // 2 WG/CU (132KB < 160KB)

    k0_prep<<<144, 256, 0, stream>>>(mux0, mux1, mux2, U0, U1, U2);
    kfuse<<<512, 1024, LDS_BYTES, stream>>>(images, U0, U1, U2, prob);
    k6_linear<<<512, 256, 0, stream>>>(prob, W, bv, out);
}

// Round 10
// 339.837 us; speedup vs baseline: 1.3316x; 1.3316x over previous
//
#include <hip/hip_runtime.h>
#include <math.h>

// ===========================================================================
// PCSQCNN fully fused: FRQI encode -> [QFT2D -> mux -> IQFT2D -> pool]^3
//                      -> |.|^2 -> linear   (linear head fused, round 19)
//
// History: r10 fused kfuse; r11-r16 six allocator levers -> all null
// (VGPR=64 immovable for 1024-thr blocks; state part-spilled to scratch);
// r17 occupancy+scalars -> null; r18 LDS b64 -> REGRESSION (b64 needs VGPR
// pairs; at 64-VGPR budget scratch tripled 300->897MB). Best measured:
// ROUND 3 config (arrays r[8][4], dynamic 66KB LDS, __sinf): kfuse 283us,
// total 340.7us.
//
// Round 19 (this round): revert to the round-3 kernel EXACTLY and fuse
// k6_linear into kfuse's tail: at end of pass 5 each crew's lanes j<8 hold
// the crew's 64-float prob slice in registers -> dot with W (80KB,
// L2-resident) + width-8 shuffle reduce + 320-float LDS scratch (reused
// exchange buffer) -> out. Removes one kernel launch, one graph edge, and
// the 8MB prob round-trip.
//
// U tables (k0): U0 transposed [y_st][x_st]; U1 unchanged;
// U2 stored [yam][cx][cy][xam]. Ownerships: F = {2j,2j+1,64+2j,65+2j};
// F4 = {fb,fb+16,fb+64,fb+80}, fb=(j>>4)*32+(j&15).
// ===========================================================================

#define PI_F 3.14159265358979323846f
#define P_ 128

__device__ __forceinline__ float2 cmul(float2 a, float2 b) {
    return make_float2(a.x * b.x - a.y * b.y, a.x * b.y + a.y * b.x);
}
__device__ __forceinline__ float2 cadd(float2 a, float2 b) {
    return make_float2(a.x + b.x, a.y + b.y);
}
__device__ __forceinline__ float2 scl(float2 a, float s) {
    return make_float2(a.x * s, a.y * s);
}
// DIF butterfly: u' = u+v ; v' = (u-v)*w
__device__ __forceinline__ void bfly_dif(float2& u, float2& v, float2 w) {
    float tx = u.x - v.x, ty = u.y - v.y;
    u.x += v.x; u.y += v.y;
    v.x = tx * w.x - ty * w.y;
    v.y = tx * w.y + ty * w.x;
}
__device__ __forceinline__ void bfly_dif1(float2& u, float2& v) {
    float tx = u.x - v.x, ty = u.y - v.y;
    u.x += v.x; u.y += v.y;
    v.x = tx; v.y = ty;
}
// DIT inverse butterfly: t = v*conj(w); u' = u+t ; v' = u-t
__device__ __forceinline__ void bfly_dit(float2& u, float2& v, float2 w) {
    float tx = v.x * w.x + v.y * w.y, ty = v.y * w.x - v.x * w.y;
    v.x = u.x - tx; v.y = u.y - ty;
    u.x += tx; u.y += ty;
}
__device__ __forceinline__ void bfly_dit1(float2& u, float2& v) {
    float tx = v.x, ty = v.y;
    v.x = u.x - tx; v.y = u.y - ty;
    u.x += tx; u.y += ty;
}

constexpr int clog2(int v) { return v <= 1 ? 0 : 1 + clog2(v >> 1); }

// LDS exchange address: line L (0..63 per plane), idx 0..127, XOR bank
// swizzle (bijective; GF(2)-rank-verified for all ownership patterns).
__device__ __forceinline__ int pf(int L, int idx) {
    int m = ((idx & 32) ? 13 : 0) ^ ((idx & 64) ? 22 : 0);
    return L * P_ + (idx ^ m);
}

// Ownership: segment size N (<=128), stride S. Thread j (0..31 per line) owns
// idx[q] = seg*N + 4S*(jj/S) + (jj%S) + S*q.  o = jj%S (twiddle low part).
template <int N, int S>
__device__ __forceinline__ void oidx(int j, int i[4], int& o) {
    constexpr int TPS = N / 4;
    constexpr int LT = clog2(TPS);
    int s = j >> LT;
    int jj = j & (TPS - 1);
    o = jj & (S - 1);
    int base = s * N + ((jj & ~(S - 1)) << 2) + o;
    i[0] = base; i[1] = base + S; i[2] = base + 2 * S; i[3] = base + 3 * S;
}

// Two DIF levels h=2S then h=S on r[0..3] (ownership stride S)
template <int S>
__device__ __forceinline__ void dif_pair(float2 r[4], int o, const float2* tw) {
    bfly_dif(r[0], r[2], tw[o * (32 / S)]);
    bfly_dif(r[1], r[3], tw[(o + S) * (32 / S)]);
    float2 wc = tw[o * (64 / S)];
    bfly_dif(r[0], r[1], wc);
    bfly_dif(r[2], r[3], wc);
}
// Two DIT levels h=S then h=2S
template <int S>
__device__ __forceinline__ void dit_pair(float2 r[4], int o, const float2* tw) {
    float2 wc = tw[o * (64 / S)];
    bfly_dit(r[0], r[1], wc);
    bfly_dit(r[2], r[3], wc);
    bfly_dit(r[0], r[2], tw[o * (32 / S)]);
    bfly_dit(r[1], r[3], tw[(o + S) * (32 / S)]);
}

// SoA store/load of one float2
__device__ __forceinline__ void stf(float* bx, float* by, int a, float2 v) {
    bx[a] = v.x; by[a] = v.y;
}
__device__ __forceinline__ float2 ldf(const float* bx, const float* by, int a) {
    return make_float2(bx[a], by[a]);
}

// Crew exchange over all 8 register-lines. Crew g owns LDS lines 2g, 2g+1
// per plane; rounds m handle regs (m, m+4). Crew = 32 consecutive lanes of
// one wave -> wave_barrier suffices; DS pipe is in-order per wave.
__device__ __forceinline__ void xch8(float* Xp, float* Yp, int g,
                                     const int* iw, const int* ir,
                                     float2 (&r)[8][4]) {
    const int la = 2 * g, lb = 2 * g + 1;
#pragma unroll
    for (int m = 0; m < 4; ++m) {
#pragma unroll
        for (int q = 0; q < 4; ++q) {
            stf(Xp, Yp, pf(la, iw[q]), r[m][q]);
            stf(Xp, Yp, pf(lb, iw[q]), r[m + 4][q]);
        }
        __builtin_amdgcn_wave_barrier();
#pragma unroll
        for (int q = 0; q < 4; ++q) {
            r[m][q]     = ldf(Xp, Yp, pf(la, ir[q]));
            r[m + 4][q] = ldf(Xp, Yp, pf(lb, ir[q]));
        }
        __builtin_amdgcn_wave_barrier();
    }
}

template <int NW, int SW, int NR, int SR>
__device__ __forceinline__ int XC(float* Xp, float* Yp, int g, int j,
                                  float2 (&r)[8][4]) {
    int iw[4], ow, ir[4], orr;
    oidx<NW, SW>(j, iw, ow);
    oidx<NR, SR>(j, ir, orr);
    (void)ow;
    xch8(Xp, Yp, g, iw, ir, r);
    return orr;
}

// Free register 4x4 transpose within each f-block (pure renaming after
// unroll; involution, used by both transpose directions).
__device__ __forceinline__ void xpose44(float2 (&r)[8][4]) {
#pragma unroll
    for (int f0 = 0; f0 < 8; f0 += 4)
#pragma unroll
        for (int a = 0; a < 4; ++a)
#pragma unroll
            for (int bq = a + 1; bq < 4; ++bq) {
                float2 t = r[f0 + a][bq];
                r[f0 + a][bq] = r[f0 + bq][a];
                r[f0 + bq][a] = t;
            }
}

__device__ __forceinline__ void mkF(int j, int* i) {
    i[0] = 2 * j; i[1] = 2 * j + 1; i[2] = 64 + 2 * j; i[3] = 65 + 2 * j;
}
__device__ __forceinline__ void mkF4(int j, int* i) {
    int b = (j >> 4) * 32 + (j & 15);
    i[0] = b; i[1] = b + 16; i[2] = b + 64; i[3] = b + 80;
}

// 2x2 multiplex on feature pair (a = f0, b = f1) with table entry U[0..3]
__device__ __forceinline__ void muxop(const float2* __restrict__ U,
                                      float2& a, float2& b) {
    float2 p0 = a, p1 = b;
    a = cadd(cmul(U[0], p0), cmul(U[1], p1));
    b = cadd(cmul(U[2], p0), cmul(U[3], p1));
}

// --- Transpose A: Y-pass -> X-pass. Source standard layout, positions
// is[4] (current Y-ownership). Chunk c=(fc,h) writes regs fc*4+2h+{0,1}
// into LDS [Xl][Y] (rotation swizzle), then refills the SAME two phys
// first-indices with the new X-positions q' in {2h,2h+1}.
// MODE 0: q'-position X = j+32q' (Xl = j+32e) -> pass starts at oidx<128,32>.
// MODE 1: q'-position X = 64h+2j+e (Xl = 2j+e) -> pass starts at F.
// Ends with xpose44 -> standard layout.
template <int MODE>
__device__ __forceinline__ void tposeA(float* Xp, float* Yp, int g, int j,
                                       const int* is, float2 (&r)[8][4]) {
#pragma unroll
    for (int c = 0; c < 4; ++c) {
        const int fc = c >> 1, h = c & 1;
        __syncthreads();
#pragma unroll
        for (int e = 0; e < 2; ++e) {
            const int k = fc * 4 + 2 * h + e;
            const int Xl = g + 32 * e;   // line X = 64h + g + 32e
#pragma unroll
            for (int q = 0; q < 4; ++q) {
                int a = Xl * P_ + ((is[q] + Xl) & 127);
                Xp[a] = r[k][q].x; Yp[a] = r[k][q].y;
            }
        }
        __syncthreads();
#pragma unroll
        for (int e = 0; e < 2; ++e) {
            const int Xl = (MODE == 0) ? (j + 32 * e) : (2 * j + e);
#pragma unroll
            for (int d = 0; d < 4; ++d) {
                int a = Xl * P_ + ((g + 32 * d + Xl) & 127);
                r[fc * 4 + 2 * h + e][d] = make_float2(Xp[a], Yp[a]);
            }
        }
    }
    __syncthreads();
    xpose44(r);
}

// --- Transpose B: X-pass -> Y-pass. xpose44 first (standard -> swapped);
// source X-ownership is[4] must have position q in X-half q>>1 (F / F4).
// Dest fills standard slots r[fc*4+dx][qy] at Y-positions id[4].
__device__ __forceinline__ void tposeB(float* Xp, float* Yp, int g, int j,
                                       const int* is, const int* id,
                                       float2 (&r)[8][4]) {
    xpose44(r);
#pragma unroll
    for (int c = 0; c < 4; ++c) {
        const int fc = c >> 1, h = c & 1;
        __syncthreads();
#pragma unroll
        for (int e = 0; e < 2; ++e) {
            const int q = 2 * h + e;
            const int Xl = is[q] & 63;
#pragma unroll
            for (int d = 0; d < 4; ++d) {
                int a = Xl * P_ + ((g + 32 * d + Xl) & 127);
                float2 v = r[fc * 4 + q][d];
                Xp[a] = v.x; Yp[a] = v.y;
            }
        }
        __syncthreads();
#pragma unroll
        for (int e = 0; e < 2; ++e) {
            const int Xl = g + 32 * e;   // dest line X = 64h + g + 32e
#pragma unroll
            for (int qy = 0; qy < 4; ++qy) {
                int a = Xl * P_ + ((id[qy] + Xl) & 127);
                r[fc * 4 + 2 * h + e][qy] = make_float2(Xp[a], Yp[a]);
            }
        }
    }
    __syncthreads();
}

// ---------------------------------------------------------------------------
// K0: precompute multiplex U tables, pre-permuted by bit-reversal.
//   U0: TRANSPOSED  idx = y_st*128 + x_st
//   U1: unchanged   idx = ((cx*2+cy)*64 + xam)*64 + yam
//   U2: TRANSPOSED  idx = ((yam*2 + cx)*2 + cy)*32 + xam
// ---------------------------------------------------------------------------
__global__ __launch_bounds__(256) void k0_prep(const float* __restrict__ mux0,
                                               const float* __restrict__ mux1,
                                               const float* __restrict__ mux2,
                                               float2* __restrict__ U0,
                                               float2* __restrict__ U1,
                                               float2* __restrict__ U2) {
    int t = blockIdx.x * 256 + threadIdx.x;
    const float* src;
    float2* dst;
    if (t < 16384) {
        int xb = t >> 7, yb = t & 127;
        int rx = __brev((unsigned)xb) >> 25;
        int ry = __brev((unsigned)yb) >> 25;
        src = mux0 + ((size_t)rx * 128 + ry) * 3;
        dst = U0 + ((size_t)yb * 128 + xb) * 4;
    } else if (t < 32768) {
        int u = t - 16384;
        int yam = u & 63, xam = (u >> 6) & 63, cy = (u >> 12) & 1, cx = (u >> 13) & 1;
        int rx = __brev((unsigned)xam) >> 26;
        int ry = __brev((unsigned)yam) >> 26;
        src = mux1 + ((size_t)(((cx * 2 + cy) * 64 + rx) * 64 + ry)) * 3;
        dst = U1 + (size_t)u * 4;
    } else if (t < 36864) {
        int u = t - 32768;
        int yam = u & 31, xam = (u >> 5) & 31, cy = (u >> 10) & 1, cx = (u >> 11) & 1;
        int rx = __brev((unsigned)xam) >> 27;
        int ry = __brev((unsigned)yam) >> 27;
        src = mux2 + ((size_t)(((cx * 2 + cy) * 32 + rx) * 32 + ry)) * 3;
        dst = U2 + ((size_t)(((yam * 2 + cx) * 2 + cy) * 32 + xam)) * 4;
    } else {
        return;
    }
    float ax = src[0], ay = src[1], az = src[2];
    float r = sqrtf(ax * ax + ay * ay + az * az + 1e-20f);
    float cr = cosf(r);
    float snr = sinf(r) / r;
    dst[0] = make_float2(cr, -az * snr);
    dst[1] = make_float2(-ay * snr, -ax * snr);
    dst[2] = make_float2(ay * snr, -ax * snr);
    dst[3] = make_float2(cr, az * snr);
}

// ---------------------------------------------------------------------------
// KFUSE: whole pipeline per image INCLUDING the linear head. 1024 threads.
// Round-3 body (arrays, dynamic LDS, __sinf) + fused k6 tail.
// ---------------------------------------------------------------------------
__global__ __attribute__((amdgpu_flat_work_group_size(1024, 1024)))
__attribute__((amdgpu_waves_per_eu(4, 4)))
void kfuse(const float* __restrict__ img,
           const float2* __restrict__ U0,
           const float2* __restrict__ U1,
           const float2* __restrict__ U2,
           const float* __restrict__ W,
           const float* __restrict__ bv,
           float* __restrict__ out) {
    extern __shared__ float smem[];
    float* Xp = smem;                       // 8192 floats
    float* Yp = smem + 8192;                // 8192 floats
    float2* tw = (float2*)(smem + 16384);   // 64 float2

    const int tid = threadIdx.x;
    const int b = blockIdx.x;
    const int g = tid >> 5;
    const int j = tid & 31;

    if (tid < 64) {
        // native sin/cos: |angle| < 2*pi, no reduction needed
        float ang = -(2.0f * PI_F / 128.0f) * (float)tid;
        tw[tid] = make_float2(__cosf(ang), __sinf(ang));
    }

    float2 r[8][4];
    int o;

    // ================= pass 1 (Y): FRQI encode + FFT_Y128 =================
    {
        const float* ib = img + (size_t)b * 16384;
#pragma unroll
        for (int k = 0; k < 4; ++k) {
            const float* ip = ib + (g + 32 * k) * 128;
#pragma unroll
            for (int q = 0; q < 4; ++q) {
                float v = ip[j + 32 * q];
                float ang = 0.5f * PI_F * v;      // in [0, pi/2)
                float c = __cosf(ang), s = __sinf(ang);  // native, call-free
                r[k][q]     = make_float2(c * (1.0f / 128.0f), 0.0f);  // f=0
                r[k + 4][q] = make_float2(s * (1.0f / 128.0f), 0.0f);  // f=1
            }
        }
    }
    __syncthreads();  // tw visible
#pragma unroll
    for (int k = 0; k < 8; ++k) dif_pair<32>(r[k], j, tw);            // h=64,32
    o = XC<128, 32, 128, 8>(Xp, Yp, g, j, r);
#pragma unroll
    for (int k = 0; k < 8; ++k) dif_pair<8>(r[k], o, tw);             // h=16,8
    o = XC<128, 8, 128, 2>(Xp, Yp, g, j, r);
#pragma unroll
    for (int k = 0; k < 8; ++k) dif_pair<2>(r[k], o, tw);             // h=4,2
    o = XC<128, 2, 128, 1>(Xp, Yp, g, j, r);
#pragma unroll
    for (int k = 0; k < 8; ++k) { bfly_dif1(r[k][0], r[k][1]); bfly_dif1(r[k][2], r[k][3]); }

    // ================= T_A1 =================
    {
        int is[4] = {4 * j, 4 * j + 1, 4 * j + 2, 4 * j + 3};
        tposeA<0>(Xp, Yp, g, j, is, r);
    }

    // ====== pass 2 (X): FFT_X128 -> M0 -> IFFT_X128 -> FFT_X64 ======
#pragma unroll
    for (int k = 0; k < 8; ++k) dif_pair<32>(r[k], j, tw);
    o = XC<128, 32, 128, 8>(Xp, Yp, g, j, r);
#pragma unroll
    for (int k = 0; k < 8; ++k) dif_pair<8>(r[k], o, tw);
    o = XC<128, 8, 128, 2>(Xp, Yp, g, j, r);
#pragma unroll
    for (int k = 0; k < 8; ++k) dif_pair<2>(r[k], o, tw);
    o = XC<128, 2, 128, 1>(Xp, Yp, g, j, r);
#pragma unroll
    for (int k = 0; k < 8; ++k) { bfly_dif1(r[k][0], r[k][1]); bfly_dif1(r[k][2], r[k][3]); }
    // M0 at x_st = 4j+q, y_st = g+32k (register-local f pair!)
#pragma unroll
    for (int k = 0; k < 4; ++k) {
        const float2* Ub = U0 + ((size_t)(g + 32 * k) * 128 + 4 * j) * 4;
#pragma unroll
        for (int q = 0; q < 4; ++q) muxop(Ub + (size_t)q * 4, r[k][q], r[k + 4][q]);
    }
    // IFFT_X128: [1,2] -> [4,8] -> [16,32] -> [64]
#pragma unroll
    for (int k = 0; k < 8; ++k) dit_pair<1>(r[k], 0, tw);
    o = XC<128, 1, 128, 4>(Xp, Yp, g, j, r);
#pragma unroll
    for (int k = 0; k < 8; ++k) dit_pair<4>(r[k], o, tw);
    o = XC<128, 4, 128, 16>(Xp, Yp, g, j, r);
#pragma unroll
    for (int k = 0; k < 8; ++k) dit_pair<16>(r[k], o, tw);
    o = XC<128, 16, 128, 32>(Xp, Yp, g, j, r);
#pragma unroll
    for (int k = 0; k < 8; ++k) { bfly_dit(r[k][0], r[k][2], tw[o]); bfly_dit(r[k][1], r[k][3], tw[o + 32]); }
    // fused FFT64 h=32 (per 64-half), o = j
#pragma unroll
    for (int k = 0; k < 8; ++k) { float2 w = tw[2 * o]; bfly_dif(r[k][0], r[k][1], w); bfly_dif(r[k][2], r[k][3], w); }
    o = XC<128, 32, 64, 8>(Xp, Yp, g, j, r);
#pragma unroll
    for (int k = 0; k < 8; ++k) dif_pair<8>(r[k], o, tw);             // h=16,8
    o = XC<64, 8, 64, 2>(Xp, Yp, g, j, r);
#pragma unroll
    for (int k = 0; k < 8; ++k) dif_pair<2>(r[k], o, tw);             // h=4,2
    {   // -> F ownership (2 positions per 64-half, needed by T_B1)
        int iw_[4], o_, ir_[4];
        oidx<64, 2>(j, iw_, o_);
        mkF(j, ir_);
        xch8(Xp, Yp, g, iw_, ir_, r);
    }
#pragma unroll
    for (int k = 0; k < 8; ++k) {
        bfly_dif1(r[k][0], r[k][1]); bfly_dif1(r[k][2], r[k][3]);     // h=1
        const float sc = 1.0f / 128.0f;                               // IFFT128 norm
#pragma unroll
        for (int q = 0; q < 4; ++q) r[k][q] = scl(r[k][q], sc);
    }

    // ================= T_B1 =================
    {
        int is[4], id[4];
        mkF(j, is);
        id[0] = 4 * j; id[1] = 4 * j + 1; id[2] = 4 * j + 2; id[3] = 4 * j + 3;
        tposeB(Xp, Yp, g, j, is, id, r);
    }

    // == pass 3 (Y): IFFT_Y128 -> FFT_Y64 -> M1 -> IFFT_Y64 -> FFT_Y32 ==
#pragma unroll
    for (int k = 0; k < 8; ++k) dit_pair<1>(r[k], 0, tw);
    o = XC<128, 1, 128, 4>(Xp, Yp, g, j, r);
#pragma unroll
    for (int k = 0; k < 8; ++k) dit_pair<4>(r[k], o, tw);
    o = XC<128, 4, 128, 16>(Xp, Yp, g, j, r);
#pragma unroll
    for (int k = 0; k < 8; ++k) dit_pair<16>(r[k], o, tw);
    o = XC<128, 16, 128, 32>(Xp, Yp, g, j, r);
#pragma unroll
    for (int k = 0; k < 8; ++k) { bfly_dit(r[k][0], r[k][2], tw[o]); bfly_dit(r[k][1], r[k][3], tw[o + 32]); }
#pragma unroll
    for (int k = 0; k < 8; ++k) { float2 w = tw[2 * o]; bfly_dif(r[k][0], r[k][1], w); bfly_dif(r[k][2], r[k][3], w); }
    o = XC<128, 32, 64, 8>(Xp, Yp, g, j, r);
#pragma unroll
    for (int k = 0; k < 8; ++k) dif_pair<8>(r[k], o, tw);
    o = XC<64, 8, 64, 2>(Xp, Yp, g, j, r);
#pragma unroll
    for (int k = 0; k < 8; ++k) dif_pair<2>(r[k], o, tw);
    o = XC<64, 2, 64, 1>(Xp, Yp, g, j, r);
#pragma unroll
    for (int k = 0; k < 8; ++k) { bfly_dif1(r[k][0], r[k][1]); bfly_dif1(r[k][2], r[k][3]); }
    // M1 at E1: y_st = s*64 + 4jj + q; lines x_st = g+32k
    {
        const int s = j >> 4, jj = j & 15;
#pragma unroll
        for (int k = 0; k < 4; ++k) {
            const int cx = k >> 1;
            const int xam = g + 32 * (k & 1);
            const float2* Ub =
                U1 + ((size_t)((((((cx << 1) | s) << 6) | xam) << 6) | (4 * jj))) * 4;
#pragma unroll
            for (int q = 0; q < 4; ++q) muxop(Ub + (size_t)q * 4, r[k][q], r[k + 4][q]);
        }
    }
    // IFFT_Y64: [1,2] -> [4,8] -> [16,32]
#pragma unroll
    for (int k = 0; k < 8; ++k) dit_pair<1>(r[k], 0, tw);
    o = XC<64, 1, 64, 4>(Xp, Yp, g, j, r);
#pragma unroll
    for (int k = 0; k < 8; ++k) dit_pair<4>(r[k], o, tw);
    o = XC<64, 4, 64, 16>(Xp, Yp, g, j, r);
#pragma unroll
    for (int k = 0; k < 8; ++k) dit_pair<16>(r[k], o, tw);
    // fused FFT32 h=16 (o = jj at E16)
#pragma unroll
    for (int k = 0; k < 8; ++k) { float2 w = tw[4 * o]; bfly_dif(r[k][0], r[k][1], w); bfly_dif(r[k][2], r[k][3], w); }
    o = XC<64, 16, 32, 4>(Xp, Yp, g, j, r);
#pragma unroll
    for (int k = 0; k < 8; ++k) dif_pair<4>(r[k], o, tw);             // h=8,4
    o = XC<32, 4, 32, 1>(Xp, Yp, g, j, r);
#pragma unroll
    for (int k = 0; k < 8; ++k) {
        dif_pair<1>(r[k], 0, tw);                                     // h=2,1
        const float sc = 1.0f / 8192.0f;                              // IFFT128*IFFT64
#pragma unroll
        for (int q = 0; q < 4; ++q) r[k][q] = scl(r[k][q], sc);
    }

    // ================= T_A2 (dest positions = F) =================
    {
        int is[4], o_;
        oidx<32, 1>(j, is, o_);
        tposeA<1>(Xp, Yp, g, j, is, r);
    }

    // ====== pass 4 (X): IFFT_X64 -> FFT_X32 -> M2 -> IFFT_X32 ======
    // start at F: h=1 pairs (2j,2j+1), (64+2j, 64+2j+1), w=1
#pragma unroll
    for (int k = 0; k < 8; ++k) { bfly_dit1(r[k][0], r[k][1]); bfly_dit1(r[k][2], r[k][3]); }
    {
        int iw_[4], ir_[4], o_;
        mkF(j, iw_);
        oidx<64, 2>(j, ir_, o_);
        xch8(Xp, Yp, g, iw_, ir_, r);
        o = o_;
    }
#pragma unroll
    for (int k = 0; k < 8; ++k) dit_pair<2>(r[k], o, tw);             // h=2,4
    o = XC<64, 2, 64, 8>(Xp, Yp, g, j, r);
#pragma unroll
    for (int k = 0; k < 8; ++k) dit_pair<8>(r[k], o, tw);             // h=8,16
    o = XC<64, 8, 64, 16>(Xp, Yp, g, j, r);
#pragma unroll
    for (int k = 0; k < 8; ++k) { bfly_dit(r[k][0], r[k][2], tw[2 * o]); bfly_dit(r[k][1], r[k][3], tw[2 * (o + 16)]); }  // h=32
    // fused FFT32 h=16
#pragma unroll
    for (int k = 0; k < 8; ++k) { float2 w = tw[4 * o]; bfly_dif(r[k][0], r[k][1], w); bfly_dif(r[k][2], r[k][3], w); }
    o = XC<64, 16, 32, 4>(Xp, Yp, g, j, r);
#pragma unroll
    for (int k = 0; k < 8; ++k) dif_pair<4>(r[k], o, tw);
    o = XC<32, 4, 32, 1>(Xp, Yp, g, j, r);
#pragma unroll
    for (int k = 0; k < 8; ++k) dif_pair<1>(r[k], 0, tw);
    // M2 at D1: x_st = s4*32 + 4jj8 + q; lines y_st = g+32k
    {
        const int s4 = j >> 3, jj8 = j & 7;
#pragma unroll
        for (int k = 0; k < 4; ++k) {
            const float2* Ub =
                U2 + ((size_t)((((g << 2) | ((s4 & 1) << 1) | (k & 1)) << 5) | (4 * jj8))) * 4;
#pragma unroll
            for (int q = 0; q < 4; ++q) muxop(Ub + (size_t)q * 4, r[k][q], r[k + 4][q]);
        }
    }
    // IFFT_X32: [1,2] -> [4,8] -> [16] (end at F4 for T_B2)
#pragma unroll
    for (int k = 0; k < 8; ++k) dit_pair<1>(r[k], 0, tw);
    o = XC<32, 1, 32, 4>(Xp, Yp, g, j, r);
#pragma unroll
    for (int k = 0; k < 8; ++k) dit_pair<4>(r[k], o, tw);
    {
        int iw_[4], o_, ir_[4];
        oidx<32, 4>(j, iw_, o_);
        mkF4(j, ir_);
        xch8(Xp, Yp, g, iw_, ir_, r);
    }
    {
        const int m = j & 15;
#pragma unroll
        for (int k = 0; k < 8; ++k) {
            float2 w = tw[4 * m];                                     // h=16
            bfly_dit(r[k][0], r[k][1], w);
            bfly_dit(r[k][2], r[k][3], w);
            const float sc = 1.0f / 2048.0f;                          // IFFT64*IFFT32
#pragma unroll
            for (int q = 0; q < 4; ++q) r[k][q] = scl(r[k][q], sc);
        }
    }

    // ================= T_B2 =================
    {
        int is[4], id[4], o_;
        mkF4(j, is);
        oidx<32, 1>(j, id, o_);
        tposeB(Xp, Yp, g, j, is, id, r);
    }

    // ========== pass 5 (Y): IFFT_Y32 + |.|^2 marginal ==========
#pragma unroll
    for (int k = 0; k < 8; ++k) dit_pair<1>(r[k], 0, tw);
    o = XC<32, 1, 32, 4>(Xp, Yp, g, j, r);
#pragma unroll
    for (int k = 0; k < 8; ++k) dit_pair<4>(r[k], o, tw);
    o = XC<32, 4, 32, 8>(Xp, Yp, g, j, r);
#pragma unroll
    for (int k = 0; k < 8; ++k) { bfly_dit(r[k][0], r[k][2], tw[4 * o]); bfly_dit(r[k][1], r[k][3], tw[4 * o + 32]); }  // h=16
    // prob + FUSED LINEAR HEAD.
    // flat prob index (per image): g*64 + (jj + 8q)*2 + f, with p2[f][q]*C.
    {
        float p2[2][4];
#pragma unroll
        for (int f = 0; f < 2; ++f)
#pragma unroll
            for (int q = 0; q < 4; ++q) {
                float s = 0.0f;
#pragma unroll
                for (int d = 0; d < 4; ++d) {
                    float2 v = r[f * 4 + d][q];
                    s += v.x * v.x + v.y * v.y;
                }
                s += __shfl_xor(s, 8);
                s += __shfl_xor(s, 16);
                p2[f][q] = s;
            }
        // reuse the (retired) exchange LDS as reduction scratch
        float* redf = smem;
        __syncthreads();   // all prior LDS ops done before reuse
        if ((j >> 3) == 0) {
            const float C = 1.0f / 1024.0f;
            const float* Wb = W + g * 64 + j * 2;
            float d0, d1, d2, d3, d4, d5, d6, d7, d8, d9;
#define DOT_C(CI, DC) { const float* wr = Wb + (CI) * 2048; \
            DC = C * (p2[0][0] * wr[0]  + p2[1][0] * wr[1]  + \
                      p2[0][1] * wr[16] + p2[1][1] * wr[17] + \
                      p2[0][2] * wr[32] + p2[1][2] * wr[33] + \
                      p2[0][3] * wr[48] + p2[1][3] * wr[49]); }
            DOT_C(0, d0) DOT_C(1, d1) DOT_C(2, d2) DOT_C(3, d3) DOT_C(4, d4)
            DOT_C(5, d5) DOT_C(6, d6) DOT_C(7, d7) DOT_C(8, d8) DOT_C(9, d9)
#undef DOT_C
#define RED8(DC) { DC += __shfl_down(DC, 4, 8); DC += __shfl_down(DC, 2, 8); \
                   DC += __shfl_down(DC, 1, 8); }
            RED8(d0) RED8(d1) RED8(d2) RED8(d3) RED8(d4)
            RED8(d5) RED8(d6) RED8(d7) RED8(d8) RED8(d9)
#undef RED8
            if (j == 0) {
                float* rg = redf + g * 10;
                rg[0] = d0; rg[1] = d1; rg[2] = d2; rg[3] = d3; rg[4] = d4;
                rg[5] = d5; rg[6] = d6; rg[7] = d7; rg[8] = d8; rg[9] = d9;
            }
        }
        __syncthreads();
        if (tid < 10) {
            float s = bv[tid];
            for (int g2 = 0; g2 < 32; ++g2) s += redf[g2 * 10 + tid];
            out[b * 10 + tid] = s;
        }
    }
}

// ---------------------------------------------------------------------------
extern "C" void kernel_launch(void* const* d_in, const int* in_sizes, int n_in,
                              void* d_out, int out_size, void* d_ws,
                              size_t ws_size, hipStream_t stream) {
    const float* images = (const float*)d_in[0];
    const float* mux0 = (const float*)d_in[1];
    const float* mux1 = (const float*)d_in[2];
    const float* mux2 = (const float*)d_in[3];
    const float* W = (const float*)d_in[4];
    const float* bv = (const float*)d_in[5];
    float* out = (float*)d_out;

    float2* U0 = (float2*)d_ws;
    float2* U1 = U0 + 65536;
    float2* U2 = U1 + 65536;
    const size_t needed = (size_t)(65536 + 65536 + 16384) * sizeof(float2);
    if (ws_size < needed) return;

    const int LDS_BYTES = (16384 + 128) * 4;  // Xp|Yp planes + tw = 66048 B

    k0_prep<<<144, 256, 0, stream>>>(mux0, mux1, mux2, U0, U1, U2);
    kfuse<<<512, 1024, LDS_BYTES, stream>>>(images, U0, U1, U2, W, bv, out);
}